// Round 1
// baseline (794.463 us; speedup 1.0000x reference)
//
#include <hip/hip_runtime.h>
#include <hip/hip_bf16.h>

// Problem constants (from reference): B=4096, F=16, H=1280, N=8, R=64, TAU=1
#define Bn 4096
#define Fn 16
#define Hn 1280
#define Nn 8
#define Rn 64
#define Cn (Fn * Hn)   // 20480 = flattened feature dim
#define EPSF 1e-12f

#define XS_LDA  (Hn + 8)   // bf16 row stride 1288 (2576B): +16B pad breaks 32-bank aliasing
#define MID_LDA (Rn + 8)   // 72

typedef __bf16 bf16x8 __attribute__((ext_vector_type(8)));
typedef float  f32x4  __attribute__((ext_vector_type(4)));

// f32 -> bf16 round-to-nearest-even (bit trick; inputs are finite)
static __device__ __forceinline__ unsigned short f2b(float f) {
  unsigned int u = __float_as_uint(f);
  u += 0x7fffu + ((u >> 16) & 1u);
  return (unsigned short)(u >> 16);
}

static __device__ __forceinline__ bf16x8 as_bf(uint4 v) {
  union { uint4 u; bf16x8 b; } c; c.u = v; return c.b;
}

// ---- prep: per-expert gate row inverse norms (8 rows x 20480) ----
__global__ __launch_bounds__(256) void prep_gate_norms(const float* __restrict__ gate_w,
                                                       float* __restrict__ gwinv) {
  const int n = blockIdx.x;
  const float4* row = (const float4*)(gate_w + (size_t)n * Cn);
  float ss = 0.f;
  for (int i = threadIdx.x; i < Cn / 4; i += 256) {
    float4 v = row[i];
    ss += v.x * v.x + v.y * v.y + v.z * v.z + v.w * v.w;
  }
#pragma unroll
  for (int off = 32; off; off >>= 1) ss += __shfl_down(ss, off, 64);
  __shared__ float red[4];
  if ((threadIdx.x & 63) == 0) red[threadIdx.x >> 6] = ss;
  __syncthreads();
  if (threadIdx.x == 0) {
    float t = red[0] + red[1] + red[2] + red[3];
    gwinv[n] = 1.f / fmaxf(sqrtf(t), EPSF);
  }
}

// ---- prep: convert down_w / up_w (each 655360 f32) to bf16 in ws ----
__global__ __launch_bounds__(256) void prep_cvt_weights(const float4* __restrict__ dw4,
                                                        const float4* __restrict__ uw4,
                                                        ushort4* __restrict__ dwb4,
                                                        ushort4* __restrict__ uwb4) {
  int i = blockIdx.x * 256 + threadIdx.x;
  if (i < (Nn * Rn * Hn) / 4) {
    float4 d = dw4[i];
    ushort4 s; s.x = f2b(d.x); s.y = f2b(d.y); s.z = f2b(d.z); s.w = f2b(d.w);
    dwb4[i] = s;
    float4 v = uw4[i];
    ushort4 t; t.x = f2b(v.x); t.y = f2b(v.y); t.z = f2b(v.z); t.w = f2b(v.w);
    uwb4[i] = t;
  }
}

// ---- fused: gating (f32) + argmax + LoRA down/up (bf16 MFMA), one block per b ----
__global__ __launch_bounds__(512) void moe_lora_fused(
    const float* __restrict__ x, const float* __restrict__ u,
    const float* __restrict__ gate_w, const float* __restrict__ sigma_p,
    const float* __restrict__ gwinv,
    const unsigned short* __restrict__ dwb, const unsigned short* __restrict__ uwb,
    float* __restrict__ out) {

  __shared__ unsigned short xs[Fn * XS_LDA];    // 41216 B: x[b] as bf16
  __shared__ unsigned short mids[Fn * MID_LDA]; // 2304 B: mid as bf16
  __shared__ float part[8 * 256];               // 8192 B: phase-B partials
  __shared__ float red[8][12];                  // wave partials: [ss, dot0..7]
  __shared__ int sel_s;

  const int b    = blockIdx.x;
  const int tid  = threadIdx.x;
  const int lane = tid & 63;
  const int wave = tid >> 6;

  // ---------- Phase A: stream x row once; f32 sumsq + 8 gate dots; stage bf16 x ----------
  const float4* xb4 = (const float4*)(x + (size_t)b * Cn);
  float ss = 0.f;
  float dot[Nn];
#pragma unroll
  for (int n = 0; n < Nn; ++n) dot[n] = 0.f;

  for (int i = tid; i < Cn / 4; i += 512) {   // 10 iterations, fully coalesced float4
    float4 v = xb4[i];
    ss += v.x * v.x + v.y * v.y + v.z * v.z + v.w * v.w;
#pragma unroll
    for (int n = 0; n < Nn; ++n) {
      float4 w = ((const float4*)(gate_w + (size_t)n * Cn))[i];
      dot[n] += v.x * w.x + v.y * w.y + v.z * w.z + v.w * w.w;
    }
    int f = i / (Hn / 4);
    int c = (i % (Hn / 4)) * 4;
    ushort4 s4;
    s4.x = f2b(v.x); s4.y = f2b(v.y); s4.z = f2b(v.z); s4.w = f2b(v.w);
    *(ushort4*)&xs[f * XS_LDA + c] = s4;
  }

  // reduce 9 values: wave shuffle, then cross-wave via LDS
#pragma unroll
  for (int off = 32; off; off >>= 1) {
    ss += __shfl_down(ss, off, 64);
#pragma unroll
    for (int n = 0; n < Nn; ++n) dot[n] += __shfl_down(dot[n], off, 64);
  }
  if (lane == 0) {
    red[wave][0] = ss;
#pragma unroll
    for (int n = 0; n < Nn; ++n) red[wave][1 + n] = dot[n];
  }
  __syncthreads();

  if (tid == 0) {
    float tss = 0.f, td[Nn];
#pragma unroll
    for (int n = 0; n < Nn; ++n) td[n] = 0.f;
#pragma unroll
    for (int w = 0; w < 8; ++w) {
      tss += red[w][0];
#pragma unroll
      for (int n = 0; n < Nn; ++n) td[n] += red[w][1 + n];
    }
    float inv_xn = 1.f / fmaxf(sqrtf(tss), EPSF);
    float sg = *sigma_p;
    float best = -3.4e38f;
    int sel = 0;
#pragma unroll
    for (int n = 0; n < Nn; ++n) {
      float logit = sg * (td[n] * inv_xn * gwinv[n]);
      float uu = u[(size_t)b * Nn + n];
      float g = -logf(-logf(uu + EPSF) + EPSF);   // gumbel; argmax of logits+g == argmax of softmax
      float y = logit + g;
      if (y > best) { best = y; sel = n; }        // first-max wins, matches jnp.argmax
    }
    sel_s = sel;
  }
  __syncthreads();
  const int e = sel_s;

  // ---------- Phase B: mid[16,64] = x_b(bf16) @ down_w[e]^T, K=1280 ----------
  // 8 waves = 4 r-tiles x 2 k-halves (640 each = 20 MFMA steps)
  const int rt  = wave & 3;
  const int kh  = wave >> 2;
  const int l16 = lane & 15;
  const int q   = lane >> 4;     // 0..3

  const unsigned short* dwe = dwb + (size_t)e * (Rn * Hn)
                            + (size_t)(rt * 16 + l16) * Hn + kh * 640 + q * 8;
  const unsigned short* axp = xs + l16 * XS_LDA + kh * 640 + q * 8;

  f32x4 acc = {0.f, 0.f, 0.f, 0.f};
#pragma unroll 4
  for (int s = 0; s < 20; ++s) {
    bf16x8 af = as_bf(*(const uint4*)(axp + s * 32));   // A[m=l16][k=q*8+j]
    bf16x8 bf = as_bf(*(const uint4*)(dwe + s * 32));   // B[n=r][k=q*8+j]
    acc = __builtin_amdgcn_mfma_f32_16x16x32_bf16(af, bf, acc, 0, 0, 0);
  }
  *(f32x4*)&part[wave * 256 + lane * 4] = acc;
  __syncthreads();

  // combine the two k-halves, convert mid to bf16 (waves 0..3)
  if (wave < 4) {
    f32x4 p0 = *(const f32x4*)&part[wave * 256 + lane * 4];
    f32x4 p1 = *(const f32x4*)&part[(wave + 4) * 256 + lane * 4];
#pragma unroll
    for (int j = 0; j < 4; ++j) {
      float sm = p0[j] + p1[j];
      int f = q * 4 + j;              // D row = (lane>>4)*4 + reg
      int r = wave * 16 + l16;        // D col = lane&15
      mids[f * MID_LDA + r] = f2b(sm);
    }
  }
  __syncthreads();

  // ---------- Phase C: out[16,1280] = mid(bf16) @ up_w[e]^T, K=64 ----------
  const unsigned short* uwe = uwb + (size_t)e * (Hn * Rn);
  bf16x8 a0 = as_bf(*(const uint4*)&mids[l16 * MID_LDA + q * 8]);        // k 0..31
  bf16x8 a1 = as_bf(*(const uint4*)&mids[l16 * MID_LDA + 32 + q * 8]);   // k 32..63
  float* outb = out + (size_t)b * Cn;

  for (int t = wave; t < Hn / 16; t += 8) {   // 10 h-tiles per wave
    const unsigned short* up = uwe + (size_t)(t * 16 + l16) * Rn + q * 8;
    bf16x8 b0 = as_bf(*(const uint4*)(up));
    bf16x8 b1 = as_bf(*(const uint4*)(up + 32));
    f32x4 o = {0.f, 0.f, 0.f, 0.f};
    o = __builtin_amdgcn_mfma_f32_16x16x32_bf16(a0, b0, o, 0, 0, 0);
    o = __builtin_amdgcn_mfma_f32_16x16x32_bf16(a1, b1, o, 0, 0, 0);
    float* op = outb + (size_t)(q * 4) * Hn + t * 16 + l16;
    op[0]      = o[0];
    op[Hn]     = o[1];
    op[2 * Hn] = o[2];
    op[3 * Hn] = o[3];
  }
}

extern "C" void kernel_launch(void* const* d_in, const int* in_sizes, int n_in,
                              void* d_out, int out_size, void* d_ws, size_t ws_size,
                              hipStream_t stream) {
  const float* x      = (const float*)d_in[0];  // [4096,16,1280]
  const float* u      = (const float*)d_in[1];  // [4096,8]
  const float* gate_w = (const float*)d_in[2];  // [8,20480]
  const float* sigma  = (const float*)d_in[3];  // scalar
  const float* down_w = (const float*)d_in[4];  // [8,64,1280]
  const float* up_w   = (const float*)d_in[5];  // [8,1280,64]
  float* out = (float*)d_out;                   // [4096,16,1280] f32

  // ws layout: [0,32) gwinv f32[8]; [64, 64+1310720) down_w bf16; then up_w bf16.
  // Total 2,621,504 bytes.
  float* gwinv = (float*)d_ws;
  unsigned short* dwb = (unsigned short*)((char*)d_ws + 64);
  unsigned short* uwb = dwb + (size_t)Nn * Rn * Hn;

  prep_gate_norms<<<Nn, 256, 0, stream>>>(gate_w, gwinv);
  prep_cvt_weights<<<((Nn * Rn * Hn) / 4 + 255) / 256, 256, 0, stream>>>(
      (const float4*)down_w, (const float4*)up_w, (ushort4*)dwb, (ushort4*)uwb);
  moe_lora_fused<<<Bn, 512, 0, stream>>>(x, u, gate_w, sigma, gwinv, dwb, uwb, out);
}